// Round 8
// baseline (716.981 us; speedup 1.0000x reference)
//
#include <hip/hip_runtime.h>
#include <math.h>

#define B_ 2
#define L_ 1024
#define DM 256
#define NL_ 6
#define DI_ 512
#define DS_ 16
#define DC_ 4
#define NC_ 10
#define ALPHA_ 0.1f
#define LC 32
#define NCH (L_/LC)            // 32 chunks
#define NCHAIN (B_*DI_*DS_)    // 16384 chains
#define BETA_LC 0.034336838202925124f  // 0.9^32

typedef unsigned short ushort_t;
typedef __attribute__((ext_vector_type(8))) short s16x8;      // 8 bf16 (MFMA A/B frag)
typedef __attribute__((ext_vector_type(4))) float f32x4;      // MFMA C/D frag
typedef __attribute__((ext_vector_type(8))) unsigned short u16x8;

__device__ __forceinline__ float sigmoidf_(float x){ return 1.f/(1.f+__expf(-x)); }
__device__ __forceinline__ ushort_t f2bf(float f){
  union{float f;unsigned u;} c; c.f=f; unsigned u=c.u;
  return (ushort_t)((u + 0x7fffu + ((u>>16)&1u))>>16);
}
__device__ __forceinline__ float bf2f(ushort_t h){
  union{unsigned u;float f;} c; c.u = ((unsigned)h)<<16; return c.f;
}

// ---------------- embed ----------------
__global__ void k_embed(const float* __restrict__ emb, const float* __restrict__ pos,
                        const int* __restrict__ ids, float* __restrict__ h){
  int row = blockIdx.x;
  int t = row & (L_-1);
  int d = threadIdx.x;
  int v = ids[row];
  h[(size_t)row*DM + d] = emb[(size_t)v*DM + d] + pos[(size_t)t*DM + d];
}

// ---------------- fp32 -> bf16 weight conversion (4 weight sets, one launch) ----------------
__global__ void k_cvt4(const float* __restrict__ a, const float* __restrict__ b2,
                       const float* __restrict__ c3, const float* __restrict__ d4,
                       ushort_t* __restrict__ oa, ushort_t* __restrict__ ob,
                       ushort_t* __restrict__ oc, ushort_t* __restrict__ od,
                       int na, int nb, int nc2, int nd){
  int k = (blockIdx.x*256 + threadIdx.x)*4;
  const float* src; ushort_t* dst;
  if (k < na){ src=a; dst=oa; }
  else { k -= na;
    if (k < nb){ src=b2; dst=ob; }
    else { k -= nb;
      if (k < nc2){ src=c3; dst=oc; }
      else { k -= nc2;
        if (k >= nd) return;
        src=d4; dst=od; } } }
  float4 v = *reinterpret_cast<const float4*>(&src[k]);
  ushort4 r;
  r.x = f2bf(v.x); r.y = f2bf(v.y); r.z = f2bf(v.z); r.w = f2bf(v.w);
  *reinterpret_cast<ushort4*>(&dst[k]) = r;
}

// ================= FUSED-A: LN + in_proj GEMM + conv/SiLU + x_proj + dt_proj + scanA =================
// Grid (NCH, B_), 512 threads. One block owns chunk j (32 seq rows) of batch b.
// A-tile = 48 rows (16-row overlap with previous chunk for conv history; zeroed at j=0).
#define OFF_HN   0        // ushort [48][264]   (GEMM)
#define OFF_WS   25344    // ushort [128][264]  (GEMM, per N-tile)
#define OFF_SXB  92928    // ushort [48][520]   (x-half GEMM out, conv in)
#define OFF_SXC  0        // ushort [32][520]   (conv out; over HN/WS after GEMM)
#define OFF_SXW  33280    // ushort [48][520]   (x_proj weights)
#define OFF_SDT  83200    // float  [32][16]    (dt)
#define OFF_SBB  85248    // float  [32][16]    (B)
#define OFF_SDEL 92928    // ushort [32][520]   (delta; over SXB after conv)
#define OFF_SDTW 126208   // ushort [512][16]   (dt_proj weights)
#define SMEM_SZ  142848

__global__ __launch_bounds__(512) void k_fusedA(
    const float* __restrict__ h, const ushort_t* __restrict__ Wip,
    const float* __restrict__ lw, const float* __restrict__ lb,
    const float* __restrict__ cw, const float* __restrict__ cb,
    const ushort_t* __restrict__ xpwb, const ushort_t* __restrict__ dtwb,
    const float* __restrict__ dtb, const float* __restrict__ A_log,
    ushort_t* __restrict__ xcb, ushort_t* __restrict__ szb,
    float* __restrict__ xdbl, float4* __restrict__ smry)
{
  __shared__ __align__(16) char smem[SMEM_SZ];
  ushort_t* HN  = (ushort_t*)(smem + OFF_HN);
  ushort_t* WS  = (ushort_t*)(smem + OFF_WS);
  ushort_t* SXB = (ushort_t*)(smem + OFF_SXB);
  ushort_t* SXC = (ushort_t*)(smem + OFF_SXC);
  ushort_t* SXW = (ushort_t*)(smem + OFF_SXW);
  float*    SDT = (float*)(smem + OFF_SDT);
  float*    SBB = (float*)(smem + OFF_SBB);
  ushort_t* SDEL= (ushort_t*)(smem + OFF_SDEL);
  ushort_t* SDTW= (ushort_t*)(smem + OFF_SDTW);

  int j = blockIdx.x, b = blockIdx.y;
  int m0 = b*L_ + j*LC;
  int tid = threadIdx.x;
  int lane = tid & 63, wv = tid >> 6;

  // ---- Phase LN: rows m0-16 .. m0+31 -> HN bf16 (rows<0 of chunk 0 zeroed = conv zero-pad)
  if (tid < 384){
    int r = tid >> 3, s = tid & 7;
    if (j == 0 && r < 16){
      ushort4 z4; z4.x=z4.y=z4.z=z4.w=0;
      #pragma unroll
      for (int i=0;i<8;i++)
        *reinterpret_cast<ushort4*>(&HN[r*264 + s*32 + i*4]) = z4;
    } else {
      int gr = m0 - 16 + r;
      const float* src = &h[(size_t)gr*DM + s*32];
      float4 v[8]; float s1=0.f, s2=0.f;
      #pragma unroll
      for (int i=0;i<8;i++){
        v[i] = *reinterpret_cast<const float4*>(src + i*4);
        s1 += v[i].x+v[i].y+v[i].z+v[i].w;
        s2 += v[i].x*v[i].x+v[i].y*v[i].y+v[i].z*v[i].z+v[i].w*v[i].w;
      }
      s1 += __shfl_xor(s1,1); s2 += __shfl_xor(s2,1);
      s1 += __shfl_xor(s1,2); s2 += __shfl_xor(s2,2);
      s1 += __shfl_xor(s1,4); s2 += __shfl_xor(s2,4);
      float mean = s1*(1.f/DM);
      float rstd = rsqrtf(s2*(1.f/DM) - mean*mean + 1e-5f);
      #pragma unroll
      for (int i=0;i<8;i++){
        int c = s*32 + i*4;
        ushort4 o;
        o.x = f2bf((v[i].x-mean)*rstd*lw[c+0]+lb[c+0]);
        o.y = f2bf((v[i].y-mean)*rstd*lw[c+1]+lb[c+1]);
        o.z = f2bf((v[i].z-mean)*rstd*lw[c+2]+lb[c+2]);
        o.w = f2bf((v[i].w-mean)*rstd*lw[c+3]+lb[c+3]);
        *reinterpret_cast<ushort4*>(&HN[r*264 + c]) = o;
      }
    }
  }
  __syncthreads();

  // ---- Phase GEMM: 8 N-tiles of 128 cols. Tiles 0..3 = x-half (48 rows -> SXB LDS);
  //      tiles 4..7 = z-half (32 rows -> silu -> szb global).
  int fr = lane & 15, fk = (lane>>4)<<3;
  int cr = (lane>>4)<<2, cc = lane & 15;
  for (int nt=0; nt<8; ++nt){
    {
      int r = tid >> 2, q = tid & 3;
      const ushort_t* src = &Wip[(size_t)(nt*128 + r)*DM + q*64];
      #pragma unroll
      for (int i=0;i<8;i++)
        *reinterpret_cast<u16x8*>(&WS[r*264 + q*64 + i*8]) =
          *reinterpret_cast<const u16x8*>(src + i*8);
    }
    __syncthreads();
    if (nt < 4){
      #pragma unroll
      for (int i=0;i<3;i++){
        int u = wv*3 + i; int s_c = u & 7, s_r = u >> 3;
        f32x4 acc = {};
        #pragma unroll
        for (int ks=0; ks<8; ++ks){
          s16x8 af = *reinterpret_cast<const s16x8*>(&HN[(s_r*16+fr)*264 + ks*32 + fk]);
          s16x8 bf = *reinterpret_cast<const s16x8*>(&WS[(s_c*16+fr)*264 + ks*32 + fk]);
          acc = __builtin_amdgcn_mfma_f32_16x16x32_bf16(af, bf, acc, 0,0,0);
        }
        #pragma unroll
        for (int rg=0; rg<4; ++rg)
          SXB[(s_r*16 + cr + rg)*520 + nt*128 + s_c*16 + cc] = f2bf(acc[rg]);
      }
    } else {
      #pragma unroll
      for (int i=0;i<2;i++){
        int u = wv*2 + i; int s_c = u & 7, s_r = u >> 3;
        f32x4 acc = {};
        #pragma unroll
        for (int ks=0; ks<8; ++ks){
          s16x8 af = *reinterpret_cast<const s16x8*>(&HN[(16 + s_r*16+fr)*264 + ks*32 + fk]);
          s16x8 bf = *reinterpret_cast<const s16x8*>(&WS[(s_c*16+fr)*264 + ks*32 + fk]);
          acc = __builtin_amdgcn_mfma_f32_16x16x32_bf16(af, bf, acc, 0,0,0);
        }
        #pragma unroll
        for (int rg=0; rg<4; ++rg){
          float v = acc[rg];
          float sv = v * sigmoidf_(v);
          szb[(size_t)(m0 + s_r*16 + cr + rg)*DI_ + (nt-4)*128 + s_c*16 + cc] = f2bf(sv);
        }
      }
    }
    __syncthreads();
  }

  // ---- Phase conv + SiLU: out rows 0..31 (SXB rows 16..47), per thread 4 rows x 8 d
  {
    int c8 = (tid & 63) * 8;
    int r4 = (tid >> 6) * 4;
    float cwv[8][4]; float cbv[8];
    #pragma unroll
    for (int e=0;e<8;e++){
      float4 w4 = *reinterpret_cast<const float4*>(&cw[(c8+e)*4]);
      cwv[e][0]=w4.x; cwv[e][1]=w4.y; cwv[e][2]=w4.z; cwv[e][3]=w4.w;
      cbv[e] = cb[c8+e];
    }
    #pragma unroll
    for (int rr=0; rr<4; ++rr){
      int t2 = r4 + rr;
      u16x8 ov;
      #pragma unroll
      for (int e=0;e<8;e++){
        float acc = cbv[e];
        #pragma unroll
        for (int k=0;k<4;k++)
          acc = fmaf(cwv[e][k], bf2f(SXB[(13 + t2 + k)*520 + c8 + e]), acc);
        float sv = acc * sigmoidf_(acc);
        ov[e] = (short)f2bf(sv);
      }
      *reinterpret_cast<u16x8*>(&SXC[t2*520 + c8]) = ov;
      *reinterpret_cast<u16x8*>(&xcb[(size_t)(m0+t2)*DI_ + c8]) = ov;
    }
  }
  __syncthreads();

  // ---- stage x_proj weights (bf16) + dt_proj weights (bf16)
  {
    #pragma unroll
    for (int i=0;i<6;i++){
      int t4 = i*512 + tid;            // 48*64 = 3072 u16x8 tasks
      int o = t4 >> 6, k8 = (t4 & 63) * 8;
      *reinterpret_cast<u16x8*>(&SXW[o*520 + k8]) =
        *reinterpret_cast<const u16x8*>(&xpwb[(size_t)o*DI_ + k8]);
    }
    int d = tid;
    *reinterpret_cast<u16x8*>(&SDTW[d*16])   = *reinterpret_cast<const u16x8*>(&dtwb[d*16]);
    *reinterpret_cast<u16x8*>(&SDTW[d*16+8]) = *reinterpret_cast<const u16x8*>(&dtwb[d*16+8]);
  }
  __syncthreads();

  // ---- Phase x_proj: thread (r, p) computes outs {p, p+16, p+32} over K=512
  {
    int r = tid >> 4, p = tid & 15;
    float a0=0.f, a1=0.f, a2=0.f;
    const ushort_t* xr = &SXC[r*520];
    #pragma unroll 4
    for (int k8=0; k8<512; k8+=8){
      u16x8 xv = *reinterpret_cast<const u16x8*>(&xr[k8]);
      u16x8 w0 = *reinterpret_cast<const u16x8*>(&SXW[p*520 + k8]);
      u16x8 w1 = *reinterpret_cast<const u16x8*>(&SXW[(p+16)*520 + k8]);
      u16x8 w2 = *reinterpret_cast<const u16x8*>(&SXW[(p+32)*520 + k8]);
      #pragma unroll
      for (int e=0;e<8;e++){
        float xf = bf2f((ushort_t)xv[e]);
        a0 = fmaf(xf, bf2f((ushort_t)w0[e]), a0);
        a1 = fmaf(xf, bf2f((ushort_t)w1[e]), a1);
        a2 = fmaf(xf, bf2f((ushort_t)w2[e]), a2);
      }
    }
    SDT[r*16+p] = a0;
    SBB[r*16+p] = a1;
    size_t xb = (size_t)(m0 + r)*48;
    xdbl[xb + p]      = a0;
    xdbl[xb + 16 + p] = a1;
    xdbl[xb + 32 + p] = a2;
  }
  __syncthreads();

  // ---- Phase dt_proj + softplus -> SDEL (bf16), thread = d
  {
    int d = tid;
    u16x8 wa = *reinterpret_cast<const u16x8*>(&SDTW[d*16]);
    u16x8 wb = *reinterpret_cast<const u16x8*>(&SDTW[d*16+8]);
    float wk[16];
    #pragma unroll
    for (int e=0;e<8;e++){ wk[e] = bf2f((ushort_t)wa[e]); wk[8+e] = bf2f((ushort_t)wb[e]); }
    float bias = dtb[d];
    #pragma unroll
    for (int t=0;t<LC;t++){
      const float* sd = &SDT[t*16];
      float acc = bias;
      #pragma unroll
      for (int k=0;k<16;k++) acc = fmaf(sd[k], wk[k], acc);
      float sp = (acc>20.f)? acc : log1pf(__expf(acc));
      SDEL[t*520 + d] = f2bf(sp);
    }
  }
  __syncthreads();

  // ---- Phase scanA: thread = d, 16 chains (n), 32 steps; cp = exp(a_n * sum(delta))
  {
    int d = tid;
    float a[16];
    #pragma unroll
    for (int q=0;q<4;q++){
      float4 v = *reinterpret_cast<const float4*>(&A_log[d*DS_ + q*4]);
      a[q*4+0] = -__expf(v.x); a[q*4+1] = -__expf(v.y);
      a[q*4+2] = -__expf(v.z); a[q*4+3] = -__expf(v.w);
    }
    float hs[16], hh[16];
    #pragma unroll
    for (int n=0;n<16;n++){ hs[n]=0.f; hh[n]=0.f; }
    float sumdv = 0.f;
    #pragma unroll 4
    for (int t=0;t<LC;t++){
      float dv = bf2f(SDEL[t*520 + d]);
      float xv = bf2f(SXC[t*520 + d]);
      float cmn = dv * xv;
      sumdv += dv;
      const float* sb = &SBB[t*16];
      #pragma unroll
      for (int n=0;n<16;n++){
        float dA = __expf(dv * a[n]);
        float dBu = cmn * sb[n];
        float mix = fmaf(ALPHA_, hs[n]-hh[n], hh[n]);
        hs[n] = fmaf(dA, hs[n], dBu);
        hh[n] = fmaf(dA, mix, dBu);
      }
    }
    size_t base = (size_t)j*NCHAIN + (size_t)(b*DI_ + d)*DS_;
    #pragma unroll
    for (int n=0;n<16;n++){
      float cp = __expf(a[n]*sumdv);
      smry[base + n] = float4{cp, hs[n], hh[n], 0.f};
    }
  }
}

// ================= chunked scan passes B & C =================
__global__ __launch_bounds__(256) void k_scanB(const float4* __restrict__ smry,
    float2* __restrict__ initArr){
  int g = blockIdx.x, b = blockIdx.y;
  int c = (b*DI_ + g*16)*DS_ + threadIdx.x;
  float hs=0.f, hh=0.f;
  #pragma unroll
  for (int j=0;j<NCH;j++){
    size_t o = (size_t)j*NCHAIN + c;
    float4 v = smry[o];
    initArr[o] = float2{hs,hh};
    float snew = fmaf(v.x, hs, v.y);
    hh = fmaf(v.x, fmaf(BETA_LC, hh-hs, hs), v.z);
    hs = snew;
  }
}

// Pass C: load init, delta on the fly, re-run chunk, gate with precomputed silu(z), write y2 bf16
__global__ __launch_bounds__(256) void k_scanC(const ushort_t* __restrict__ xcb,
    const float* __restrict__ xdbl, const ushort_t* __restrict__ szb,
    const float* __restrict__ dtw, const float* __restrict__ dtb,
    const float* __restrict__ A_log, const float* __restrict__ Dp,
    const float2* __restrict__ initArr, ushort_t* __restrict__ y2b){
  int j = blockIdx.x, g = blockIdx.y, b = blockIdx.z;
  int tid = threadIdx.x;
  int n = tid&15, dg = tid>>4;
  int d0 = g*16;
  int mbase = b*L_ + j*LC;
  int chain = (b*DI_+d0)*DS_ + tid;
  float2 iv = initArr[(size_t)j*NCHAIN + chain];   // issue early
  __shared__ float sbd[LC][48];
  __shared__ float sdtw[16][16];
  __shared__ float sxv[LC][16];
  __shared__ float sdel[LC][16];
  __shared__ float sz[LC][16];
  __shared__ float sy[LC][16];
  {
    const float4* xsrc = reinterpret_cast<const float4*>(xdbl + (size_t)mbase*48);
    reinterpret_cast<float4*>(&sbd[0][0])[tid] = xsrc[tid];
    if (tid < 128) reinterpret_cast<float4*>(&sbd[0][0])[256+tid] = xsrc[256+tid];
    if (tid < 64){
      int row = tid>>1, half = tid&1;
      u16x8 v = *reinterpret_cast<const u16x8*>(&xcb[(size_t)(mbase+row)*DI_ + d0 + half*8]);
      #pragma unroll
      for (int e=0;e<8;e++) sxv[row][half*8+e] = bf2f((ushort_t)v[e]);
    } else if (tid < 128){
      int s = tid-64, row = s>>1, half = s&1;
      u16x8 v = *reinterpret_cast<const u16x8*>(&szb[(size_t)(mbase+row)*DI_ + d0 + half*8]);
      #pragma unroll
      for (int e=0;e<8;e++) sz[row][half*8+e] = bf2f((ushort_t)v[e]);
    } else if (tid < 192){
      int s = tid-128, row = s>>2, c4 = (s&3)<<2;
      *reinterpret_cast<float4*>(&sdtw[row][c4]) =
        *reinterpret_cast<const float4*>(&dtw[(size_t)(d0+row)*16 + c4]);
    }
  }
  __syncthreads();
  #pragma unroll
  for (int q=0;q<2;q++){
    int p = q*256 + tid;
    int t = p>>4, dd = p&15;
    float acc = dtb[d0+dd];
    #pragma unroll
    for (int k=0;k<16;k++) acc = fmaf(sbd[t][k], sdtw[dd][k], acc);
    sdel[t][dd] = (acc>20.f)? acc : log1pf(__expf(acc));
  }
  __syncthreads();
  float a = -__expf(A_log[(d0+dg)*DS_ + n]);
  float hs = iv.x, hh = iv.y;
  #pragma unroll
  for (int tt=0; tt<LC; tt+=8){
    float dA8[8], dBu8[8], yv8[8];
    #pragma unroll
    for (int t=0;t<8;t++){
      float dv = sdel[tt+t][dg];
      dA8[t]  = __expf(dv*a);
      dBu8[t] = dv * sxv[tt+t][dg] * sbd[tt+t][16+n];
    }
    #pragma unroll
    for (int t=0;t<8;t++){
      float mix = fmaf(ALPHA_, hs-hh, hh);
      hs = fmaf(dA8[t], hs, dBu8[t]);
      hh = fmaf(dA8[t], mix, dBu8[t]);
      yv8[t] = hh * sbd[tt+t][32+n];
    }
    #pragma unroll
    for (int t=0;t<8;t++){
      yv8[t] += __shfl_xor(yv8[t],1,16);
      yv8[t] += __shfl_xor(yv8[t],2,16);
      yv8[t] += __shfl_xor(yv8[t],4,16);
      yv8[t] += __shfl_xor(yv8[t],8,16);
    }
    if (n==0){
      #pragma unroll
      for (int t=0;t<8;t++) sy[tt+t][dg] = yv8[t];
    }
  }
  __syncthreads();
  float dpv = Dp[d0 + (tid&15)];
  #pragma unroll
  for (int idx=0; idx<2; ++idx){
    int flat = idx*256 + tid;
    int t2 = flat>>4, dd = flat&15;
    float xvv = sxv[t2][dd];
    float szv = sz [t2][dd];
    float yfin = (sy[t2][dd] + dpv*xvv) * szv;
    y2b[(size_t)(mbase + t2)*DI_ + d0 + dd] = f2bf(yfin);
  }
}

// ---------------- out_proj GEMM (bf16 MFMA) + residual, h += y2 @ W^T ----------------
__global__ __launch_bounds__(256) void k_gemm_out(const ushort_t* __restrict__ A,
    const ushort_t* __restrict__ W, float* __restrict__ h){
  __shared__ ushort_t As[32][264];
  __shared__ ushort_t Ws[64][264];
  int bm = blockIdx.y<<5, bn = blockIdx.x<<6;
  int tid = threadIdx.x;
  int lane = tid&63, wid = tid>>6;
  int wm = (wid>>1)<<4, wn = (wid&1)<<5;
  int fr = lane&15, fk = (lane>>4)<<3;
  f32x4 acc[2] = {};
  for (int k0=0;k0<DI_;k0+=256){
    {
      int r = tid>>3, q = tid&7;
      const ushort_t* src = &A[(size_t)(bm+r)*DI_ + k0 + q*32];
      #pragma unroll
      for (int i=0;i<4;i++)
        *reinterpret_cast<u16x8*>(&As[r][q*32+i*8]) = *reinterpret_cast<const u16x8*>(src+i*8);
      int r2 = tid>>2, q2 = tid&3;
      const ushort_t* ws = &W[(size_t)(bn+r2)*DI_ + k0 + q2*64];
      #pragma unroll
      for (int i=0;i<8;i++)
        *reinterpret_cast<u16x8*>(&Ws[r2][q2*64+i*8]) = *reinterpret_cast<const u16x8*>(ws+i*8);
    }
    __syncthreads();
    #pragma unroll
    for (int k=0;k<256;k+=32){
      s16x8 a0 = *reinterpret_cast<const s16x8*>(&As[wm+fr][k+fk]);
      s16x8 b0 = *reinterpret_cast<const s16x8*>(&Ws[wn+fr][k+fk]);
      s16x8 b1 = *reinterpret_cast<const s16x8*>(&Ws[wn+16+fr][k+fk]);
      acc[0] = __builtin_amdgcn_mfma_f32_16x16x32_bf16(a0,b0,acc[0],0,0,0);
      acc[1] = __builtin_amdgcn_mfma_f32_16x16x32_bf16(a0,b1,acc[1],0,0,0);
    }
    __syncthreads();
  }
  int cr = (lane>>4)<<2, cc = lane&15;
  #pragma unroll
  for (int jj=0;jj<2;jj++){
    int row = bm + wm + cr;
    int col = bn + wn + (jj<<4) + cc;
    #pragma unroll
    for (int r=0;r<4;r++){
      size_t idx2 = (size_t)(row+r)*DM + col;
      h[idx2] += acc[jj][r];
    }
  }
}

// ---------------- masked pooling ----------------
__global__ __launch_bounds__(256) void k_pool(const float* __restrict__ h,
    const int* __restrict__ mask, float* __restrict__ partial){
  int p = blockIdx.x, b = blockIdx.y, d = threadIdx.x;
  int t0 = p*64;
  __shared__ float sm[64];
  if (d < 64) sm[d] = (float)mask[b*L_ + t0 + d];
  __syncthreads();
  const float* hp = &h[(size_t)(b*L_ + t0)*DM + d];
  float s = 0.f;
  #pragma unroll 8
  for (int i=0;i<64;i++)
    s = fmaf(sm[i], hp[(size_t)i*DM], s);
  partial[(size_t)(b*16+p)*DM + d] = s;
}

// ---------------- final: count + LN + classifier ----------------
__global__ __launch_bounds__(256) void k_head(const float* __restrict__ partial,
    const int* __restrict__ mask, const float* __restrict__ nw, const float* __restrict__ nb,
    const float* __restrict__ cw, const float* __restrict__ cb, float* __restrict__ out){
  int b = blockIdx.x, d = threadIdx.x;
  int4 mi = *reinterpret_cast<const int4*>(&mask[b*L_ + d*4]);
  float cnt = (float)(mi.x + mi.y + mi.z + mi.w);
  #pragma unroll
  for (int o=32;o>0;o>>=1) cnt += __shfl_down(cnt,o);
  __shared__ float ac[4];
  __shared__ float scnt;
  int wid = d>>6, lane = d&63;
  if (lane==0) ac[wid] = cnt;
  __syncthreads();
  if (d==0) scnt = ac[0]+ac[1]+ac[2]+ac[3];
  __syncthreads();
  float s = 0.f;
  #pragma unroll
  for (int p=0;p<16;p++) s += partial[(size_t)(b*16+p)*DM + d];
  float v = s / scnt;
  float s1 = v, s2 = v*v;
  #pragma unroll
  for (int o=32;o>0;o>>=1){ s1 += __shfl_down(s1,o); s2 += __shfl_down(s2,o); }
  __shared__ float a1[4], a2[4];
  __shared__ float mv[2];
  if (lane==0){ a1[wid]=s1; a2[wid]=s2; }
  __syncthreads();
  if (d==0){
    float t1=a1[0]+a1[1]+a1[2]+a1[3];
    float t2=a2[0]+a2[1]+a2[2]+a2[3];
    float m = t1/(float)DM;
    mv[0]=m; mv[1]=rsqrtf(t2/(float)DM - m*m + 1e-5f);
  }
  __syncthreads();
  __shared__ float sp[DM];
  sp[d] = (v-mv[0])*mv[1]*nw[d]+nb[d];
  __syncthreads();
  __shared__ float cpart[NC_][16];
  if (d < NC_*16){
    int c = d>>4, q = d&15;
    float acc = 0.f;
    #pragma unroll
    for (int k=0;k<16;k++) acc = fmaf(sp[q*16+k], cw[(size_t)c*DM+q*16+k], acc);
    cpart[c][q] = acc;
  }
  __syncthreads();
  if (d < NC_){
    float acc = cb[d];
    #pragma unroll
    for (int q=0;q<16;q++) acc += cpart[d][q];
    out[b*NC_+d] = acc;
  }
}

extern "C" void kernel_launch(void* const* d_in, const int* in_sizes, int n_in,
                              void* d_out, int out_size, void* d_ws, size_t ws_size,
                              hipStream_t stream){
  const float* emb   = (const float*)d_in[0];
  const float* pos   = (const float*)d_in[1];
  const float* ln_w  = (const float*)d_in[2];
  const float* ln_b  = (const float*)d_in[3];
  const float* ipw   = (const float*)d_in[4];
  const float* cw    = (const float*)d_in[5];
  const float* cb    = (const float*)d_in[6];
  const float* xpw   = (const float*)d_in[7];
  const float* dtw   = (const float*)d_in[8];
  const float* dtb   = (const float*)d_in[9];
  const float* A_log = (const float*)d_in[10];
  const float* Dp    = (const float*)d_in[11];
  const float* opw   = (const float*)d_in[12];
  const float* nw    = (const float*)d_in[13];
  const float* nb    = (const float*)d_in[14];
  const float* clw   = (const float*)d_in[15];
  const float* clb   = (const float*)d_in[16];
  const int*   ids   = (const int*)d_in[17];
  const int*   mask  = (const int*)d_in[18];
  float* out = (float*)d_out;

  float* ws    = (float*)d_ws;
  float* h     = ws;                     // 524288 floats
  float* xdbl  = h + 524288;             // 98304
  float* part  = xdbl + 98304;           // 8192
  float4* smry = (float4*)(part + 8192); // 524288 float4
  float2* initA= (float2*)((float*)smry + 2097152); // 524288 float2
  ushort_t* xcb  = (ushort_t*)((float*)initA + 1048576); // 2048*512
  ushort_t* szb  = xcb + 1048576;        // 2048*512
  ushort_t* y2b  = szb + 1048576;        // 2048*512
  ushort_t* ipwb = y2b + 1048576;        // 6*1024*256
  ushort_t* opwb = ipwb + 1572864;       // 6*256*512
  ushort_t* xpwb = opwb + 786432;        // 6*48*512
  ushort_t* dtwb = xpwb + 147456;        // 6*512*16

  const int NA = 6*2*DI_*DM, NB = 6*DM*DI_, NX = 6*48*DI_, ND = 6*DI_*16;
  k_cvt4<<<dim3(((NA+NB+NX+ND)/4 + 255)/256), 256, 0, stream>>>(
      ipw, opw, xpw, dtw, ipwb, opwb, xpwb, dtwb, NA, NB, NX, ND);
  k_embed<<<dim3(B_*L_), dim3(DM), 0, stream>>>(emb, pos, ids, h);

  for (int l=0; l<NL_; ++l){
    k_fusedA<<<dim3(NCH, B_), 512, 0, stream>>>(
        h, ipwb + (size_t)l*2*DI_*DM, ln_w + l*DM, ln_b + l*DM,
        cw + l*DI_*DC_, cb + l*DI_,
        xpwb + (size_t)l*48*DI_, dtwb + (size_t)l*DI_*16,
        dtb + l*DI_, A_log + (size_t)l*DI_*DS_,
        xcb, szb, xdbl, smry);
    k_scanB<<<dim3(DI_/16, B_), 256, 0, stream>>>(smry, initA);
    k_scanC<<<dim3(NCH, DI_/16, B_), 256, 0, stream>>>(
        xcb, xdbl, szb, dtw + (size_t)l*DI_*16, dtb + l*DI_,
        A_log + (size_t)l*DI_*DS_, Dp + l*DI_, initA, y2b);
    k_gemm_out<<<dim3(DM/64, (B_*L_)/32), 256, 0, stream>>>(
        y2b, opwb + (size_t)l*DM*DI_, h);
  }
  k_pool<<<dim3(16, B_), 256, 0, stream>>>(h, mask, part);
  k_head<<<dim3(B_), 256, 0, stream>>>(part, mask, nw, nb, clw, clb, out);
}